// Round 1
// baseline (1192.397 us; speedup 1.0000x reference)
//
#include <hip/hip_runtime.h>

#define NNODES 100000
#define NEDGES 1000000
#define DIM 64
#define NGRAPHS 128
#define NLAYERS 3
#define BN_EPS 1e-5f

// workspace layout (units: 4-byte elements)
#define OFF_DEG   0
#define OFF_RP    100096
#define OFF_CUR   200128
#define OFF_ESRC  300160
#define OFF_EW    1300160
#define OFF_AGG   2300160
#define OFF_Y     8700160
#define OFF_STATS 15100160
// stats block (zeroed each call): sums[l] at +l*128 ([64] sum, [64] sumsq)
// gsum[l] at +384+l*8192; cnt at +24960; scale[l] at +25088+l*64; shift[l] at +25280+l*64
#define STATS_TOTAL 25472

__global__ void zero_kernel(int* __restrict__ p, int n) {
    for (int i = blockIdx.x * blockDim.x + threadIdx.x; i < n; i += gridDim.x * blockDim.x)
        p[i] = 0;
}

__global__ void hist_kernel(const int* __restrict__ ei, const int* __restrict__ batch,
                            int* __restrict__ deg, int* __restrict__ cnt) {
    for (int i = blockIdx.x * blockDim.x + threadIdx.x; i < NEDGES; i += gridDim.x * blockDim.x) {
        atomicAdd(&deg[ei[NEDGES + i]], 1);
        if (i < NNODES) atomicAdd(&cnt[batch[i]], 1);
    }
}

__global__ __launch_bounds__(1024) void scan_kernel(const int* __restrict__ deg,
                                                    int* __restrict__ row_ptr,
                                                    int* __restrict__ cursor) {
    __shared__ int s[1024];
    const int t = threadIdx.x;
    int running = 0;
    for (int base = 0; base < NNODES; base += 1024) {
        int i = base + t;
        int v = (i < NNODES) ? deg[i] : 0;
        __syncthreads();            // protect s[] from previous iteration's reads
        s[t] = v;
        __syncthreads();
        for (int off = 1; off < 1024; off <<= 1) {
            int x = (t >= off) ? s[t - off] : 0;
            __syncthreads();
            s[t] += x;
            __syncthreads();
        }
        int excl = s[t] - v;
        if (i < NNODES) {
            row_ptr[i] = running + excl;
            cursor[i]  = running + excl;
        }
        running += s[1023];
    }
    if (t == 0) row_ptr[NNODES] = running;
}

__global__ void build_kernel(const int* __restrict__ ei, const float* __restrict__ ea,
                             int* __restrict__ cursor, int* __restrict__ esrc,
                             float* __restrict__ ew) {
    for (int e = blockIdx.x * blockDim.x + threadIdx.x; e < NEDGES; e += gridDim.x * blockDim.x) {
        int d = ei[NEDGES + e];
        int pos = atomicAdd(&cursor[d], 1);
        esrc[pos] = ei[e];
        ew[pos] = ea[e];
    }
}

// aggregate: agg[n][c] = sum over incoming edges of w_e * (hprev[src][c]*scale[c]+shift[c])
template <bool FIRST>
__global__ __launch_bounds__(256) void agg_kernel(const float* __restrict__ hprev,
                                                  const float* __restrict__ sc,
                                                  const float* __restrict__ sh,
                                                  const int* __restrict__ row_ptr,
                                                  const int* __restrict__ esrc,
                                                  const float* __restrict__ ew,
                                                  float* __restrict__ agg) {
    const int w = (blockIdx.x * 256 + threadIdx.x) >> 6;
    const int lane = threadIdx.x & 63;
    if (w >= NNODES) return;
    const int beg = row_ptr[w], end = row_ptr[w + 1];
    const float scale = FIRST ? 1.f : sc[lane];
    const float shift = FIRST ? 0.f : sh[lane];
    float acc = 0.f;
    for (int j = beg; j < end; ++j) {
        const int s = esrc[j];
        const float wt = ew[j];
        const float hv = hprev[s * 64 + lane];
        acc += wt * (FIRST ? hv : fmaf(hv, scale, shift));
    }
    agg[w * 64 + lane] = acc;
}

// y = PReLU(agg @ W^T + bias); thread-per-row, W via wave-uniform scalar loads,
// LDS 16-column transpose staging for semi-coalesced stores.
__global__ __launch_bounds__(256) void gemm_kernel(const float* __restrict__ agg,
                                                   const float* __restrict__ W,
                                                   const float* __restrict__ bias,
                                                   const float* __restrict__ pa_ptr,
                                                   float* __restrict__ y) {
    __shared__ float tile[4][64 * 17];
    const int wv = threadIdx.x >> 6, lane = threadIdx.x & 63;
    const int tileIdx = blockIdx.x * 4 + wv;
    const int base = tileIdx * 64;
    if (base >= NNODES) return;   // whole-wave exit; no __syncthreads in this kernel
    const int row = base + lane;
    const float pa = *pa_ptr;
    float a[64];
    if (row < NNODES) {
        const float4* ap = (const float4*)(agg + row * 64);
#pragma unroll
        for (int i = 0; i < 16; ++i) {
            float4 t = ap[i];
            a[4 * i] = t.x; a[4 * i + 1] = t.y; a[4 * i + 2] = t.z; a[4 * i + 3] = t.w;
        }
    } else {
#pragma unroll
        for (int i = 0; i < 64; ++i) a[i] = 0.f;
    }
    float* tl = tile[wv];
    for (int cc = 0; cc < 4; ++cc) {
#pragma unroll
        for (int ci = 0; ci < 16; ++ci) {
            const int c = cc * 16 + ci;
            const float* wr = W + c * 64;   // wave-uniform -> s_load from K$
            float acc = bias[c];
#pragma unroll
            for (int k = 0; k < 64; k += 4) {
                const float4 w4 = *(const float4*)(wr + k);
                acc += a[k] * w4.x + a[k + 1] * w4.y + a[k + 2] * w4.z + a[k + 3] * w4.w;
            }
            const float v = (acc >= 0.f) ? acc : pa * acc;
            tl[lane * 17 + ci] = v;   // banks (17*lane+ci)%32: conflict-free (2 lanes/bank)
        }
        // wave-synchronous LDS (per-wave tile), store 64 rows x 16 cols semi-coalesced
#pragma unroll
        for (int s = 0; s < 16; ++s) {
            const int idx = s * 64 + lane;
            const int rr = idx >> 4;
            const int cl = idx & 15;
            const int grow = base + rr;
            if (grow < NNODES) y[grow * 64 + cc * 16 + cl] = tl[rr * 17 + cl];
        }
    }
}

// per-channel sum/sumsq (for BN) + per-graph sums (batch is sorted -> register
// accumulation with one atomic flush per graph-segment per wave)
__global__ __launch_bounds__(256) void stats_kernel(const float* __restrict__ y,
                                                    const int* __restrict__ batch,
                                                    float* __restrict__ sums,
                                                    float* __restrict__ gsum) {
    const int NWAVES = 2048;
    const int w = (blockIdx.x * 256 + threadIdx.x) >> 6;
    const int lane = threadIdx.x & 63;
    const int chunk = (NNODES + NWAVES - 1) / NWAVES;  // 49
    const int r0 = w * chunk;
    const int r1 = min(NNODES, r0 + chunk);
    if (r0 >= r1) return;
    float ls = 0.f, lsq = 0.f, gacc = 0.f;
    int gcur = batch[r0];
    for (int r = r0; r < r1; ++r) {
        const int g = batch[r];
        if (g != gcur) {
            atomicAdd(&gsum[gcur * 64 + lane], gacc);
            gacc = 0.f;
            gcur = g;
        }
        const float v = y[r * 64 + lane];
        gacc += v;
        ls += v;
        lsq = fmaf(v, v, lsq);
    }
    atomicAdd(&gsum[gcur * 64 + lane], gacc);
    atomicAdd(&sums[lane], ls);
    atomicAdd(&sums[64 + lane], lsq);
}

// BN closure: mean/var -> affine (scale,shift) for the next layer's lazy norm,
// pooled[g] = gsum[g]*sc + cnt[g]*sh written straight into d_out.
__global__ void finalize_kernel(const float* __restrict__ sums, const float* __restrict__ gsum,
                                const int* __restrict__ cnt, const float* __restrict__ bn_w,
                                const float* __restrict__ bn_b, float* __restrict__ scale,
                                float* __restrict__ shift, float* __restrict__ out, int layer) {
    const int tid = blockIdx.x * blockDim.x + threadIdx.x;
    if (tid >= NGRAPHS * 64) return;
    const int g = tid >> 6, c = tid & 63;
    const float mean = sums[c] * (1.f / NNODES);
    const float var = fmaxf(sums[64 + c] * (1.f / NNODES) - mean * mean, 0.f);
    const float inv = rsqrtf(var + BN_EPS);
    const float sc = inv * bn_w[c];
    const float sh = bn_b[c] - mean * sc;
    if (g == 0) { scale[c] = sc; shift[c] = sh; }
    const float pooled = gsum[tid] * sc + (float)cnt[g] * sh;
    out[g * (NLAYERS * 64) + layer * 64 + c] = pooled;
    if (layer == NLAYERS - 1) out[NGRAPHS * NLAYERS * 64 + g * 64 + c] = pooled;
}

extern "C" void kernel_launch(void* const* d_in, const int* in_sizes, int n_in,
                              void* d_out, int out_size, void* d_ws, size_t ws_size,
                              hipStream_t stream) {
    const float* x    = (const float*)d_in[0];
    const int*   ei   = (const int*)d_in[1];
    const float* ea   = (const float*)d_in[2];
    const int*   batch= (const int*)d_in[3];
    const float* W    = (const float*)d_in[4];
    const float* b    = (const float*)d_in[5];
    const float* pa   = (const float*)d_in[6];
    const float* bn_w = (const float*)d_in[7];
    const float* bn_b = (const float*)d_in[8];
    float* out = (float*)d_out;
    float* ws  = (float*)d_ws;
    int*   wsi = (int*)d_ws;

    int*   deg  = wsi + OFF_DEG;
    int*   rp   = wsi + OFF_RP;
    int*   cur  = wsi + OFF_CUR;
    int*   esrc = wsi + OFF_ESRC;
    float* ew   = ws + OFF_EW;
    float* agg  = ws + OFF_AGG;
    float* y    = ws + OFF_Y;
    float* stats = ws + OFF_STATS;
    int*   cnt  = (int*)(ws + OFF_STATS + 24960);

    zero_kernel<<<391, 256, 0, stream>>>(deg, NNODES);
    zero_kernel<<<100, 256, 0, stream>>>((int*)stats, STATS_TOTAL);
    hist_kernel<<<3907, 256, 0, stream>>>(ei, batch, deg, cnt);
    scan_kernel<<<1, 1024, 0, stream>>>(deg, rp, cur);
    build_kernel<<<3907, 256, 0, stream>>>(ei, ea, cur, esrc, ew);

    for (int l = 0; l < NLAYERS; ++l) {
        float* sums  = stats + l * 128;
        float* gsum  = stats + 384 + l * 8192;
        float* scale = stats + 25088 + l * 64;
        float* shift = stats + 25280 + l * 64;
        if (l == 0)
            agg_kernel<true><<<25000, 256, 0, stream>>>(x, nullptr, nullptr, rp, esrc, ew, agg);
        else
            agg_kernel<false><<<25000, 256, 0, stream>>>(y, stats + 25088 + (l - 1) * 64,
                                                         stats + 25280 + (l - 1) * 64,
                                                         rp, esrc, ew, agg);
        gemm_kernel<<<391, 256, 0, stream>>>(agg, W + l * 4096, b + l * 64, pa, y);
        stats_kernel<<<512, 256, 0, stream>>>(y, batch, sums, gsum);
        finalize_kernel<<<32, 256, 0, stream>>>(sums, gsum, cnt, bn_w + l * 64, bn_b + l * 64,
                                                scale, shift, out, l);
    }
}

// Round 2
// 762.425 us; speedup vs baseline: 1.5640x; 1.5640x over previous
//
#include <hip/hip_runtime.h>

#define NNODES 100000
#define NEDGES 1000000
#define DIM 64
#define NGRAPHS 128
#define NLAYERS 3
#define BN_EPS 1e-5f

#define NBINS 3125          // 32 nodes per bin, 3125*32 == NNODES exactly
#define GBLK 64             // blocks for count/scatter passes

// workspace layout (4-byte element offsets)
#define OFF_EDGES   0            // int2[NEDGES] = 2,000,000 ints
#define OFF_BINBASE 2000000      // int[NBINS+1]
#define OFF_AGG     2003200      // float[NNODES*64]
#define OFF_Y       8403200      // float[NNODES*64]
// counts/offsets/binTotal live inside the (not yet used) Y region during preprocessing
#define OFF_COUNTS  8403200      // int[NBINS*GBLK] = 200,000
#define OFF_OFFS    8603200      // int[NBINS*GBLK] = 200,000
#define OFF_BTOT    8803200      // int[NBINS]
// stats region
#define OFF_SCALE   14803200     // float[NLAYERS*64]
#define OFF_SHIFT   14803392     // float[NLAYERS*64]
#define OFF_GSUM    14803584     // float[NGRAPHS*64]
#define OFF_PS      14811776     // float[NGRAPHS*64]
#define OFF_PQ      14819968     // float[NGRAPHS*64]
#define OFF_END     14828160     // int[NGRAPHS]

// ---- preprocessing: bin 1M edges by dst>>5 with zero global atomics ----

__global__ __launch_bounds__(1024) void count_kernel(const int* __restrict__ ei,
                                                     int* __restrict__ counts) {
    __shared__ int hist[NBINS];
    const int tid = threadIdx.x, blk = blockIdx.x;
    for (int i = tid; i < NBINS; i += 1024) hist[i] = 0;
    __syncthreads();
    const int e0 = blk * (NEDGES / GBLK), e1 = e0 + (NEDGES / GBLK);
    for (int e = e0 + tid; e < e1; e += 1024)
        atomicAdd(&hist[ei[NEDGES + e] >> 5], 1);
    __syncthreads();
    for (int bin = tid; bin < NBINS; bin += 1024)
        counts[bin * GBLK + blk] = hist[bin];
}

// one wave per bin: exclusive scan of the 64 per-block counts + bin total
__global__ __launch_bounds__(256) void s1_kernel(const int* __restrict__ counts,
                                                 int* __restrict__ offs,
                                                 int* __restrict__ btot) {
    const int bin = blockIdx.x * 4 + (threadIdx.x >> 6);
    const int lane = threadIdx.x & 63;
    if (bin >= NBINS) return;
    const int v = counts[bin * GBLK + lane];
    int s = v;
    for (int off = 1; off < 64; off <<= 1) {
        int t = __shfl_up(s, off);
        if (lane >= off) s += t;
    }
    offs[bin * GBLK + lane] = s - v;
    if (lane == 63) btot[bin] = s;
}

// single-block exclusive scan over NBINS bin totals -> binBase (+ sentinel)
__global__ __launch_bounds__(1024) void s2_kernel(const int* __restrict__ btot,
                                                  int* __restrict__ binBase) {
    __shared__ int s[1024];
    const int t = threadIdx.x;
    int running = 0;
    for (int base = 0; base < NBINS; base += 1024) {
        const int i = base + t;
        const int v = (i < NBINS) ? btot[i] : 0;
        __syncthreads();
        s[t] = v;
        __syncthreads();
        for (int off = 1; off < 1024; off <<= 1) {
            int x = (t >= off) ? s[t - off] : 0;
            __syncthreads();
            s[t] += x;
            __syncthreads();
        }
        if (i < NBINS) binBase[i] = running + s[t] - v;
        running += s[1023];
    }
    if (t == 0) binBase[NBINS] = running;
}

__global__ __launch_bounds__(1024) void scatter_kernel(const int* __restrict__ ei,
                                                       const float* __restrict__ ea,
                                                       const int* __restrict__ binBase,
                                                       const int* __restrict__ offs,
                                                       int2* __restrict__ edges) {
    __shared__ int cur[NBINS];
    const int tid = threadIdx.x, blk = blockIdx.x;
    for (int i = tid; i < NBINS; i += 1024)
        cur[i] = binBase[i] + offs[i * GBLK + blk];
    __syncthreads();
    const int e0 = blk * (NEDGES / GBLK), e1 = e0 + (NEDGES / GBLK);
    for (int e = e0 + tid; e < e1; e += 1024) {
        const int dst = ei[NEDGES + e];
        const int src = ei[e];
        const float w = ea[e];
        const int pos = atomicAdd(&cur[dst >> 5], 1);   // LDS atomic
        edges[pos] = make_int2((src << 5) | (dst & 31), __float_as_int(w));
    }
}

// per-graph end offsets from the sorted batch vector (no atomics)
__global__ __launch_bounds__(1024) void bounds_kernel(const int* __restrict__ batch,
                                                      int* __restrict__ endv) {
    const int i = blockIdx.x * 1024 + threadIdx.x;
    if (i >= NNODES) return;
    const int b0 = batch[i];
    const int b1 = (i + 1 < NNODES) ? batch[i + 1] : NGRAPHS;
    for (int g = b0; g < b1; ++g) endv[g] = i + 1;
    if (i == 0)
        for (int g = 0; g < b0; ++g) endv[g] = 0;
}

// ---- aggregation: wave per bin, private 8 KB LDS accumulator (no atomics) ----
template <bool FIRST>
__global__ __launch_bounds__(256) void agg_kernel(const float* __restrict__ h,
                                                  const float* __restrict__ scale,
                                                  const float* __restrict__ shift,
                                                  const int* __restrict__ binBase,
                                                  const int2* __restrict__ edges,
                                                  float* __restrict__ agg) {
    __shared__ float accAll[4][32 * 64];
    const int w = threadIdx.x >> 6, lane = threadIdx.x & 63;
    const int bin = blockIdx.x * 4 + w;
    if (bin >= NBINS) return;             // whole-wave exit; no __syncthreads below
    float* acc = accAll[w];
#pragma unroll
    for (int r = 0; r < 32; ++r) acc[r * 64 + lane] = 0.f;
    const float sc = FIRST ? 1.f : scale[lane];
    const float sh = FIRST ? 0.f : shift[lane];
    const int beg = binBase[bin], end = binBase[bin + 1];
    for (int j = beg; j < end; j += 64) {
        const int n = min(64, end - j);
        int2 ed = (j + lane < end) ? edges[j + lane] : make_int2(0, 0);
        for (int t = 0; t < n; ++t) {
            const int sd = __shfl(ed.x, t);
            const float wt = __int_as_float(__shfl(ed.y, t));
            const float hv = h[(sd >> 5) * 64 + lane];
            const float m = FIRST ? hv * wt : fmaf(hv, sc, sh) * wt;
            acc[(sd & 31) * 64 + lane] += m;
        }
    }
    const int nodeBase = bin * 32;
#pragma unroll
    for (int r = 0; r < 32; ++r)
        agg[(nodeBase + r) * 64 + lane] = acc[r * 64 + lane];
}

// ---- y = PReLU(agg @ W^T + bias), thread-per-row, W via wave-uniform loads ----
__global__ __launch_bounds__(256) void gemm_kernel(const float* __restrict__ agg,
                                                   const float* __restrict__ W,
                                                   const float* __restrict__ bias,
                                                   const float* __restrict__ pa_ptr,
                                                   float* __restrict__ y) {
    __shared__ float tile[4][64 * 17];
    const int wv = threadIdx.x >> 6, lane = threadIdx.x & 63;
    const int base = (blockIdx.x * 4 + wv) * 64;
    if (base >= NNODES) return;           // whole-wave exit
    const int row = base + lane;
    const float pa = *pa_ptr;
    float a[64];
    if (row < NNODES) {
        const float4* ap = (const float4*)(agg + row * 64);
#pragma unroll
        for (int i = 0; i < 16; ++i) {
            float4 t = ap[i];
            a[4 * i] = t.x; a[4 * i + 1] = t.y; a[4 * i + 2] = t.z; a[4 * i + 3] = t.w;
        }
    } else {
#pragma unroll
        for (int i = 0; i < 64; ++i) a[i] = 0.f;
    }
    float* tl = tile[wv];
    for (int cc = 0; cc < 4; ++cc) {
#pragma unroll
        for (int ci = 0; ci < 16; ++ci) {
            const int c = cc * 16 + ci;
            const float* wr = W + c * 64;
            float acc = bias[c];
#pragma unroll
            for (int k = 0; k < 64; k += 4) {
                const float4 w4 = *(const float4*)(wr + k);
                acc += a[k] * w4.x + a[k + 1] * w4.y + a[k + 2] * w4.z + a[k + 3] * w4.w;
            }
            const float v = (acc >= 0.f) ? acc : pa * acc;
            tl[lane * 17 + ci] = v;
        }
#pragma unroll
        for (int s = 0; s < 16; ++s) {
            const int idx = s * 64 + lane;
            const int rr = idx >> 4, cl = idx & 15;
            const int grow = base + rr;
            if (grow < NNODES) y[grow * 64 + cc * 16 + cl] = tl[rr * 17 + cl];
        }
    }
}

// ---- block-per-graph: per-graph sum + per-channel BN partials (no atomics) ----
__global__ __launch_bounds__(256) void stats_kernel(const float* __restrict__ y,
                                                    const int* __restrict__ endv,
                                                    float* __restrict__ gsum,
                                                    float* __restrict__ pS,
                                                    float* __restrict__ pQ) {
    __shared__ float red[3][4][64];
    const int g = blockIdx.x;
    const int w = threadIdx.x >> 6, lane = threadIdx.x & 63;
    const int r0 = (g == 0) ? 0 : endv[g - 1];
    const int r1 = endv[g];
    float ga = 0.f, ls = 0.f, lsq = 0.f;
    for (int r = r0 + w; r < r1; r += 4) {
        const float v = y[r * 64 + lane];
        ga += v; ls += v; lsq = fmaf(v, v, lsq);
    }
    red[0][w][lane] = ga; red[1][w][lane] = ls; red[2][w][lane] = lsq;
    __syncthreads();
    if (w == 0) {
        float a = 0.f, b = 0.f, c = 0.f;
#pragma unroll
        for (int k = 0; k < 4; ++k) {
            a += red[0][k][lane]; b += red[1][k][lane]; c += red[2][k][lane];
        }
        gsum[g * 64 + lane] = a;
        pS[g * 64 + lane] = b;
        pQ[g * 64 + lane] = c;
    }
}

// ---- single block: BN closure + pooled outputs straight into d_out ----
__global__ __launch_bounds__(1024) void finalize_kernel(const float* __restrict__ gsum,
                                                        const float* __restrict__ pS,
                                                        const float* __restrict__ pQ,
                                                        const int* __restrict__ endv,
                                                        const float* __restrict__ bn_w,
                                                        const float* __restrict__ bn_b,
                                                        float* __restrict__ scale,
                                                        float* __restrict__ shift,
                                                        float* __restrict__ out, int layer) {
    __shared__ float ssc[64], ssh[64];
    const int tid = threadIdx.x;
    if (tid < 64) {
        float s = 0.f, q = 0.f;
        for (int g = 0; g < NGRAPHS; ++g) {
            s += pS[g * 64 + tid];
            q += pQ[g * 64 + tid];
        }
        const float mean = s * (1.f / NNODES);
        const float var = fmaxf(q * (1.f / NNODES) - mean * mean, 0.f);
        const float inv = rsqrtf(var + BN_EPS);
        const float sc = inv * bn_w[tid];
        const float sh = bn_b[tid] - mean * sc;
        ssc[tid] = sc; ssh[tid] = sh;
        scale[tid] = sc; shift[tid] = sh;
    }
    __syncthreads();
    for (int idx = tid; idx < NGRAPHS * 64; idx += 1024) {
        const int g = idx >> 6, c = idx & 63;
        const int cnt = endv[g] - ((g == 0) ? 0 : endv[g - 1]);
        const float pooled = gsum[idx] * ssc[c] + (float)cnt * ssh[c];
        out[g * (NLAYERS * 64) + layer * 64 + c] = pooled;
        if (layer == NLAYERS - 1) out[NGRAPHS * NLAYERS * 64 + idx] = pooled;
    }
}

extern "C" void kernel_launch(void* const* d_in, const int* in_sizes, int n_in,
                              void* d_out, int out_size, void* d_ws, size_t ws_size,
                              hipStream_t stream) {
    const float* x     = (const float*)d_in[0];
    const int*   ei    = (const int*)d_in[1];
    const float* ea    = (const float*)d_in[2];
    const int*   batch = (const int*)d_in[3];
    const float* W     = (const float*)d_in[4];
    const float* b     = (const float*)d_in[5];
    const float* pa    = (const float*)d_in[6];
    const float* bn_w  = (const float*)d_in[7];
    const float* bn_b  = (const float*)d_in[8];
    float* out = (float*)d_out;
    float* ws  = (float*)d_ws;
    int*   wsi = (int*)d_ws;

    int2*  edges   = (int2*)(wsi + OFF_EDGES);
    int*   binBase = wsi + OFF_BINBASE;
    float* agg     = ws + OFF_AGG;
    float* y       = ws + OFF_Y;
    int*   counts  = wsi + OFF_COUNTS;
    int*   offs    = wsi + OFF_OFFS;
    int*   btot    = wsi + OFF_BTOT;
    float* scaleA  = ws + OFF_SCALE;
    float* shiftA  = ws + OFF_SHIFT;
    float* gsum    = ws + OFF_GSUM;
    float* pS      = ws + OFF_PS;
    float* pQ      = ws + OFF_PQ;
    int*   endv    = wsi + OFF_END;

    count_kernel<<<GBLK, 1024, 0, stream>>>(ei, counts);
    s1_kernel<<<(NBINS + 3) / 4, 256, 0, stream>>>(counts, offs, btot);
    s2_kernel<<<1, 1024, 0, stream>>>(btot, binBase);
    scatter_kernel<<<GBLK, 1024, 0, stream>>>(ei, ea, binBase, offs, edges);
    bounds_kernel<<<(NNODES + 1023) / 1024, 1024, 0, stream>>>(batch, endv);

    for (int l = 0; l < NLAYERS; ++l) {
        if (l == 0)
            agg_kernel<true><<<(NBINS + 3) / 4, 256, 0, stream>>>(x, nullptr, nullptr,
                                                                  binBase, edges, agg);
        else
            agg_kernel<false><<<(NBINS + 3) / 4, 256, 0, stream>>>(y, scaleA + (l - 1) * 64,
                                                                   shiftA + (l - 1) * 64,
                                                                   binBase, edges, agg);
        gemm_kernel<<<391, 256, 0, stream>>>(agg, W + l * 4096, b + l * 64, pa, y);
        stats_kernel<<<NGRAPHS, 256, 0, stream>>>(y, endv, gsum, pS, pQ);
        finalize_kernel<<<1, 1024, 0, stream>>>(gsum, pS, pQ, endv, bn_w + l * 64,
                                                bn_b + l * 64, scaleA + l * 64,
                                                shiftA + l * 64, out, l);
    }
}